// Round 3
// baseline (151.675 us; speedup 1.0000x reference)
//
#include <hip/hip_runtime.h>
#include <math.h>

// Sizes (fixed by the reference)
#define NA 4
#define NT 64
#define NC 8
#define NK 1024
#define NR 8
#define NH 64
#define NW 64

__device__ __forceinline__ float2 cmul(float2 a, float2 b) {
    return make_float2(fmaf(a.x, b.x, -a.y * b.y), fmaf(a.x, b.y, a.y * b.x));
}

// One block per (r, a, c, k-quarter); 256 threads = 256 k points.
// Output needed by the harness is Re(y) only ([T,C,K] float32), and since
// phi/dcf/scale are real, only Re(F) is ever needed downstream.
// ATOMIC=0: write Fre[r,a,c,k] (float) to ws.  ATOMIC=1: atomically scatter
// phi*dcf*scale*Re(F) into out (out pre-zeroed via hipMemsetAsync).
template <int ATOMIC>
__global__ __launch_bounds__(256) void ndft_kernel(
    const float* __restrict__ xr, const float* __restrict__ xi,
    const float* __restrict__ mr, const float* __restrict__ mi,
    const float* __restrict__ trj,
    const float* __restrict__ phi, const float* __restrict__ dcf,
    const int* __restrict__ sidx,
    float* __restrict__ Fre, float* __restrict__ out)
{
    __shared__ float2 simg[NH * NW];   // 32 KB: img for this (a,c)
    int b = blockIdx.x;                // 1024 blocks
    int kq = b & 3;
    int c  = (b >> 2) & 7;
    int a  = (b >> 5) & 3;
    int r  = b >> 7;
    int tid = threadIdx.x;

    // Build coil image x[a]*mps[c] into LDS (coalesced global reads).
    for (int i = tid; i < NH * NW; i += 256) {
        float xre = xr[(a << 12) + i], xim = xi[(a << 12) + i];
        float mre = mr[(c << 12) + i], mim = mi[(c << 12) + i];
        simg[i] = make_float2(xre * mre - xim * mim, xre * mim + xim * mre);
    }
    __syncthreads();

    int k = (kq << 8) + tid;
    float t0 = trj[(r << 11) + k];          // trj[r,0,k] -> h axis
    float t1 = trj[(r << 11) + 1024 + k];   // trj[r,1,k] -> w axis

    float sv, cv;
    sincosf(-t1, &sv, &cv);        float2 ewb = make_float2(cv, sv);  // step exp(-i*t1)
    sincosf(32.0f * t1, &sv, &cv); float2 ews = make_float2(cv, sv);  // start exp(-i*t1*(0-32))
    sincosf(-t0, &sv, &cv);        float2 ehb = make_float2(cv, sv);  // step exp(-i*t0)
    sincosf(32.0f * t0, &sv, &cv); float2 ehc = make_float2(cv, sv);  // running exp(-i*t0*(h-32))

    float accx = 0.f;
    for (int h0 = 0; h0 < NH; h0 += 4) {
        float2 s0 = make_float2(0.f, 0.f), s1 = s0, s2 = s0, s3 = s0;
        const float2* i0 = simg + (h0 << 6);
        float2 ew = ews;                    // restart recurrence each h-block
        #pragma unroll 8
        for (int w = 0; w < NW; ++w) {
            float2 v0 = i0[w];
            float2 v1 = i0[w + 64];
            float2 v2 = i0[w + 128];
            float2 v3 = i0[w + 192];
            s0.x = fmaf(v0.x, ew.x, fmaf(-v0.y, ew.y, s0.x));
            s0.y = fmaf(v0.x, ew.y, fmaf( v0.y, ew.x, s0.y));
            s1.x = fmaf(v1.x, ew.x, fmaf(-v1.y, ew.y, s1.x));
            s1.y = fmaf(v1.x, ew.y, fmaf( v1.y, ew.x, s1.y));
            s2.x = fmaf(v2.x, ew.x, fmaf(-v2.y, ew.y, s2.x));
            s2.y = fmaf(v2.x, ew.y, fmaf( v2.y, ew.x, s2.y));
            s3.x = fmaf(v3.x, ew.x, fmaf(-v3.y, ew.y, s3.x));
            s3.y = fmaf(v3.x, ew.y, fmaf( v3.y, ew.x, s3.y));
            ew = cmul(ew, ewb);
        }
        float2 e0 = ehc;
        float2 e1 = cmul(e0, ehb);
        float2 e2 = cmul(e1, ehb);
        float2 e3 = cmul(e2, ehb);
        ehc = cmul(e3, ehb);
        // Re(s * e) = s.x*e.x - s.y*e.y
        accx = fmaf(s0.x, e0.x, fmaf(-s0.y, e0.y, accx));
        accx = fmaf(s1.x, e1.x, fmaf(-s1.y, e1.y, accx));
        accx = fmaf(s2.x, e2.x, fmaf(-s2.y, e2.y, accx));
        accx = fmaf(s3.x, e3.x, fmaf(-s3.y, e3.y, accx));
    }

    if (!ATOMIC) {
        Fre[(((r * 4 + a) * 8 + c) << 10) + k] = accx;
    } else {
        float d = dcf[(r << 10) + k] * 0.03125f;   // scale = 2/sqrt(64*64)
        for (int t = 0; t < NT; ++t) {
            if (sidx[t] == r) {
                float sc = phi[a * 64 + t] * d;
                atomicAdd(out + (t << 13) + (c << 10) + k, sc * accx);
            }
        }
    }
}

__global__ __launch_bounds__(256) void combine_kernel(
    const float* __restrict__ Fre, const float* __restrict__ phi,
    const float* __restrict__ dcf, const int* __restrict__ sidx,
    float* __restrict__ out)
{
    int idx = blockIdx.x * 256 + threadIdx.x;   // T*C*K = 524288
    if (idx >= NT * NC * NK) return;
    int k = idx & 1023;
    int c = (idx >> 10) & 7;
    int t = idx >> 13;
    int r = sidx[t];                            // I_ == 1
    float d = dcf[(r << 10) + k] * 0.03125f;
    float acc = 0.f;
    #pragma unroll
    for (int a = 0; a < 4; ++a) {
        float p = phi[a * 64 + t];
        acc = fmaf(p, Fre[(((r * 4 + a) * 8 + c) << 10) + k], acc);
    }
    out[idx] = acc * d;
}

extern "C" void kernel_launch(void* const* d_in, const int* in_sizes, int n_in,
                              void* d_out, int out_size, void* d_ws, size_t ws_size,
                              hipStream_t stream)
{
    const float* x_re   = (const float*)d_in[0];
    const float* x_im   = (const float*)d_in[1];
    const float* mps_re = (const float*)d_in[2];
    const float* mps_im = (const float*)d_in[3];
    const float* phi    = (const float*)d_in[4];
    const float* dcf    = (const float*)d_in[5];
    const float* trj    = (const float*)d_in[6];
    const int*   sidx   = (const int*)d_in[7];
    float* out = (float*)d_out;

    const size_t F_bytes = (size_t)NR * NA * NC * NK * sizeof(float);  // 1 MB

    if (ws_size >= F_bytes) {
        float* Fre = (float*)d_ws;
        hipLaunchKernelGGL((ndft_kernel<0>), dim3(1024), dim3(256), 0, stream,
                           x_re, x_im, mps_re, mps_im, trj, phi, dcf, sidx, Fre, out);
        hipLaunchKernelGGL(combine_kernel, dim3(2048), dim3(256), 0, stream,
                           Fre, phi, dcf, sidx, out);
    } else {
        hipMemsetAsync(d_out, 0, (size_t)out_size * sizeof(float), stream);
        hipLaunchKernelGGL((ndft_kernel<1>), dim3(1024), dim3(256), 0, stream,
                           x_re, x_im, mps_re, mps_im, trj, phi, dcf, sidx,
                           (float*)nullptr, out);
    }
}

// Round 4
// 25.646 us; speedup vs baseline: 5.9143x; 5.9143x over previous
//
#include <hip/hip_runtime.h>
#include <hip/hip_bf16.h>
#include <math.h>

#define NA 4
#define NT 64
#define NC 8
#define NK 1024
#define NR 8
#define NH 64
#define NW 64

typedef __attribute__((ext_vector_type(8))) short bf16x8;
typedef __attribute__((ext_vector_type(4))) float f32x4;

__device__ __forceinline__ float2 cmul2(float2 a, float2 b) {
    return make_float2(fmaf(a.x, b.x, -a.y * b.y), fmaf(a.x, b.y, a.y * b.x));
}

// ---------------------------------------------------------------------------
// prep: build A_ws (512KB bf16) in MFMA-frag-linear order.
// A logical: [m=32][k'=8192], k' = 2*hw + (re/im).  Stored so that the GEMM
// kernel's chunk staging is a LINEAR copy and ds_read_b128 frag loads are
// conflict-free:  uint slot t = ((step*2 + mt)*64 + l)*4 + i2  holds the
// (re,im) bf16 pair for m = mt*16 + (l&15), hw = step*16 + (l>>4)*4 + i2.
// ---------------------------------------------------------------------------
__global__ __launch_bounds__(256) void prep_kernel(
    const float* __restrict__ xr, const float* __restrict__ xi,
    const float* __restrict__ mr, const float* __restrict__ mi,
    uint* __restrict__ Aws)
{
    int t = blockIdx.x * 256 + threadIdx.x;    // 131072 total
    int step = t >> 9;
    int mt   = (t >> 8) & 1;
    int l    = (t >> 2) & 63;
    int i2   = t & 3;
    int hw = step * 16 + ((l >> 4) << 2) + i2;
    int m  = (mt << 4) + (l & 15);
    int a = m >> 3, c = m & 7;
    float xre = xr[(a << 12) + hw], xim = xi[(a << 12) + hw];
    float mre = mr[(c << 12) + hw], mim = mi[(c << 12) + hw];
    float re = xre * mre - xim * mim;
    float im = xre * mim + xim * mre;
    __hip_bfloat162 p = __float22bfloat162_rn(make_float2(re, im));
    union { __hip_bfloat162 h; uint u; } cv; cv.h = p;
    Aws[t] = cv.u;
}

// ---------------------------------------------------------------------------
// gemm: Re(F)[m][rk] = sum_{k'} A[m][k'] * B[rk][k'],  B generated in-register.
// 256 blocks (one per 32 k-points), 512 threads (8 waves: nsub=w&1 n-subtile,
// kq=w>>1 K-quarter-slice per chunk). A chunks (16 steps = 32KB) double
// buffered via global_load_lds.
// ---------------------------------------------------------------------------
__global__ __launch_bounds__(512) void gemm_kernel(
    const uint* __restrict__ Aws, const float* __restrict__ trj,
    float* __restrict__ Fre)
{
    __shared__ uint lds[16384];   // 64KB: two 32KB chunk buffers
    int b = blockIdx.x;           // 256
    int tid = threadIdx.x;
    int w = tid >> 6, l = tid & 63;
    int nsub = w & 1, kq = w >> 1;
    int lg = l >> 4, ln = l & 15;
    int r = b >> 5;
    int kp = ((b & 31) << 5) + (nsub << 4) + ln;   // k-point 0..1023
    float t0 = trj[(r << 11) + kp];
    float t1 = trj[(r << 11) + 1024 + kp];

    // Ew register table: ew[4j+i] = exp(-i*t1*(w-32)), w = 16j + lg*4 + i
    float sv, cv;
    float2 ew[16];
    int w0 = lg << 2;
    sincosf(t1 * (float)(32 - w0), &sv, &cv); ew[0] = make_float2(cv, sv);
    float2 st1, st16, st4h;
    sincosf(-t1, &sv, &cv);        st1  = make_float2(cv, sv);
    sincosf(-16.0f * t1, &sv, &cv); st16 = make_float2(cv, sv);
    ew[1] = cmul2(ew[0], st1);
    ew[2] = cmul2(ew[1], st1);
    ew[3] = cmul2(ew[2], st1);
    #pragma unroll
    for (int j = 1; j < 4; ++j) {
        #pragma unroll
        for (int i = 0; i < 4; ++i) ew[4*j + i] = cmul2(ew[4*(j-1) + i], st16);
    }
    // Eh: this wave sees h = ch*4 + kq (constant within a chunk)
    float2 ehc;
    sincosf(t0 * (float)(32 - kq), &sv, &cv); ehc = make_float2(cv, sv);
    sincosf(-4.0f * t0, &sv, &cv); st4h = make_float2(cv, sv);

    f32x4 acc0 = {0.f, 0.f, 0.f, 0.f}, acc1 = acc0;

    // stage chunk 0 into buffer 0
    #pragma unroll
    for (int q = 0; q < 4; ++q) {
        __builtin_amdgcn_global_load_lds(
            (const __attribute__((address_space(1))) void*)(Aws + (w*4 + q)*256 + l*4),
            (__attribute__((address_space(3))) void*)(lds + (w*4 + q)*256),
            16, 0, 0);
    }

    for (int ch = 0; ch < 16; ++ch) {
        int cur = ch & 1;
        __syncthreads();   // drains vmcnt/lgkm: current chunk resident, prev buffer free
        if (ch < 15) {
            const uint* gsrc = Aws + (ch + 1) * 8192;
            uint* ldst = lds + (cur ? 0 : 8192);
            #pragma unroll
            for (int q = 0; q < 4; ++q) {
                __builtin_amdgcn_global_load_lds(
                    (const __attribute__((address_space(1))) void*)(gsrc + (w*4 + q)*256 + l*4),
                    (__attribute__((address_space(3))) void*)(ldst + (w*4 + q)*256),
                    16, 0, 0);
            }
        }
        const uint* bufc = lds + (cur ? 8192 : 0);
        #pragma unroll
        for (int j = 0; j < 4; ++j) {
            int ls = kq * 4 + j;   // local step in chunk
            bf16x8 a0 = *(const bf16x8*)(bufc + (ls*2 + 0)*256 + l*4);
            bf16x8 a1 = *(const bf16x8*)(bufc + (ls*2 + 1)*256 + l*4);
            union { uint u[4]; bf16x8 v; } bf;
            #pragma unroll
            for (int i = 0; i < 4; ++i) {
                float2 e2 = cmul2(ehc, ew[4*j + i]);
                __hip_bfloat162 pk = __float22bfloat162_rn(make_float2(e2.x, -e2.y));
                union { __hip_bfloat162 h; uint u; } cu; cu.h = pk;
                bf.u[i] = cu.u;
            }
            acc0 = __builtin_amdgcn_mfma_f32_16x16x32_bf16(a0, bf.v, acc0, 0, 0, 0);
            acc1 = __builtin_amdgcn_mfma_f32_16x16x32_bf16(a1, bf.v, acc1, 0, 0, 0);
        }
        ehc = cmul2(ehc, st4h);
    }

    // cross-wave K-reduce (4 kq partials per nsub) via LDS
    __syncthreads();
    float* red = (float*)lds;
    int base0 = (((kq*2 + nsub)*2 + 0)*64 + l)*4;
    int base1 = (((kq*2 + nsub)*2 + 1)*64 + l)*4;
    #pragma unroll
    for (int g = 0; g < 4; ++g) { red[base0 + g] = acc0[g]; red[base1 + g] = acc1[g]; }
    __syncthreads();
    for (int e = tid; e < 1024; e += 512) {
        float s = red[e] + red[e + 1024] + red[e + 2048] + red[e + 3072];
        int reg = e & 3, lp = (e >> 2) & 63, mt = (e >> 8) & 1, ns = e >> 9;
        int m  = (mt << 4) + ((lp >> 4) << 2) + reg;   // row = (l>>4)*4+reg (verified C/D map)
        int rk = b * 32 + (ns << 4) + (lp & 15);
        Fre[(m << 13) + rk] = s;
    }
}

__global__ __launch_bounds__(256) void combine_kernel(
    const float* __restrict__ Fre, const float* __restrict__ phi,
    const float* __restrict__ dcf, const int* __restrict__ sidx,
    float* __restrict__ out)
{
    int idx = blockIdx.x * 256 + threadIdx.x;   // T*C*K = 524288
    if (idx >= NT * NC * NK) return;
    int k = idx & 1023;
    int c = (idx >> 10) & 7;
    int t = idx >> 13;
    int r = sidx[t];
    float d = dcf[(r << 10) + k] * 0.03125f;
    float acc = 0.f;
    #pragma unroll
    for (int a = 0; a < 4; ++a) {
        float p = phi[a * 64 + t];
        acc = fmaf(p, Fre[(((a << 3) + c) << 13) + (r << 10) + k], acc);
    }
    out[idx] = acc * d;
}

// ---------------- fallback (proven round-3 path, no ws needed) --------------
__global__ __launch_bounds__(256) void ndft_atomic_kernel(
    const float* __restrict__ xr, const float* __restrict__ xi,
    const float* __restrict__ mr, const float* __restrict__ mi,
    const float* __restrict__ trj,
    const float* __restrict__ phi, const float* __restrict__ dcf,
    const int* __restrict__ sidx, float* __restrict__ out)
{
    __shared__ float2 simg[NH * NW];
    int b = blockIdx.x;
    int kq = b & 3, c = (b >> 2) & 7, a = (b >> 5) & 3, r = b >> 7;
    int tid = threadIdx.x;
    for (int i = tid; i < NH * NW; i += 256) {
        float xre = xr[(a << 12) + i], xim = xi[(a << 12) + i];
        float mre = mr[(c << 12) + i], mim = mi[(c << 12) + i];
        simg[i] = make_float2(xre * mre - xim * mim, xre * mim + xim * mre);
    }
    __syncthreads();
    int k = (kq << 8) + tid;
    float t0 = trj[(r << 11) + k];
    float t1 = trj[(r << 11) + 1024 + k];
    float sv, cv;
    sincosf(-t1, &sv, &cv);        float2 ewb = make_float2(cv, sv);
    sincosf(32.0f * t1, &sv, &cv); float2 ews = make_float2(cv, sv);
    sincosf(-t0, &sv, &cv);        float2 ehb = make_float2(cv, sv);
    sincosf(32.0f * t0, &sv, &cv); float2 ehc = make_float2(cv, sv);
    float accx = 0.f;
    for (int h0 = 0; h0 < NH; h0 += 4) {
        float2 s0 = make_float2(0.f, 0.f), s1 = s0, s2 = s0, s3 = s0;
        const float2* i0 = simg + (h0 << 6);
        float2 ewc = ews;
        #pragma unroll 8
        for (int w = 0; w < NW; ++w) {
            float2 v0 = i0[w], v1 = i0[w+64], v2 = i0[w+128], v3 = i0[w+192];
            s0.x = fmaf(v0.x, ewc.x, fmaf(-v0.y, ewc.y, s0.x));
            s0.y = fmaf(v0.x, ewc.y, fmaf( v0.y, ewc.x, s0.y));
            s1.x = fmaf(v1.x, ewc.x, fmaf(-v1.y, ewc.y, s1.x));
            s1.y = fmaf(v1.x, ewc.y, fmaf( v1.y, ewc.x, s1.y));
            s2.x = fmaf(v2.x, ewc.x, fmaf(-v2.y, ewc.y, s2.x));
            s2.y = fmaf(v2.x, ewc.y, fmaf( v2.y, ewc.x, s2.y));
            s3.x = fmaf(v3.x, ewc.x, fmaf(-v3.y, ewc.y, s3.x));
            s3.y = fmaf(v3.x, ewc.y, fmaf( v3.y, ewc.x, s3.y));
            ewc = cmul2(ewc, ewb);
        }
        float2 e0 = ehc, e1 = cmul2(e0, ehb), e2 = cmul2(e1, ehb), e3 = cmul2(e2, ehb);
        ehc = cmul2(e3, ehb);
        accx = fmaf(s0.x, e0.x, fmaf(-s0.y, e0.y, accx));
        accx = fmaf(s1.x, e1.x, fmaf(-s1.y, e1.y, accx));
        accx = fmaf(s2.x, e2.x, fmaf(-s2.y, e2.y, accx));
        accx = fmaf(s3.x, e3.x, fmaf(-s3.y, e3.y, accx));
    }
    float d = dcf[(r << 10) + k] * 0.03125f;
    for (int t = 0; t < NT; ++t) {
        if (sidx[t] == r) atomicAdd(out + (t << 13) + (c << 10) + k, phi[a*64 + t] * d * accx);
    }
}

extern "C" void kernel_launch(void* const* d_in, const int* in_sizes, int n_in,
                              void* d_out, int out_size, void* d_ws, size_t ws_size,
                              hipStream_t stream)
{
    const float* x_re   = (const float*)d_in[0];
    const float* x_im   = (const float*)d_in[1];
    const float* mps_re = (const float*)d_in[2];
    const float* mps_im = (const float*)d_in[3];
    const float* phi    = (const float*)d_in[4];
    const float* dcf    = (const float*)d_in[5];
    const float* trj    = (const float*)d_in[6];
    const int*   sidx   = (const int*)d_in[7];
    float* out = (float*)d_out;

    const size_t A_bytes = 512 * 1024;                 // bf16 A matrix
    const size_t F_bytes = 32 * 8192 * sizeof(float);  // 1MB Re(F)

    if (ws_size >= A_bytes + F_bytes) {
        uint*  Aws = (uint*)d_ws;
        float* Fre = (float*)((char*)d_ws + A_bytes);
        hipLaunchKernelGGL(prep_kernel, dim3(512), dim3(256), 0, stream,
                           x_re, x_im, mps_re, mps_im, Aws);
        hipLaunchKernelGGL(gemm_kernel, dim3(256), dim3(512), 0, stream,
                           Aws, trj, Fre);
        hipLaunchKernelGGL(combine_kernel, dim3(2048), dim3(256), 0, stream,
                           Fre, phi, dcf, sidx, out);
    } else {
        hipMemsetAsync(d_out, 0, (size_t)out_size * sizeof(float), stream);
        hipLaunchKernelGGL(ndft_atomic_kernel, dim3(1024), dim3(256), 0, stream,
                           x_re, x_im, mps_re, mps_im, trj, phi, dcf, sidx, out);
    }
}